// Round 3
// baseline (281.768 us; speedup 1.0000x reference)
//
#include <hip/hip_runtime.h>

constexpr int N_CLASSES = 1000;   // 250 float4 per label row
constexpr int EMBED     = 1024;   // 256 float4 per row; 4 float4 per lane

typedef float floatx4 __attribute__((ext_vector_type(4)));

// Persistent grid-stride, wave-per-row, 2-deep ping-pong pipeline.
// Loads are PLAIN (cached) -- the 265 MB input set is ~96% of the 256 MiB
// Infinity Cache, and the bench replays over the same buffers, so allowing
// L3 allocation serves most of the stream from MALL instead of HBM. The
// earlier nontemporal hint (meant to protect mean_class in L2) forfeited
// that residency; mean_class (4 MB) is L3-resident regardless.
__global__ __launch_bounds__(256, 4) void angular_pipelined_kernel(
    const float* __restrict__ features,
    const float* __restrict__ labels,
    const float* __restrict__ mean_class,
    float* __restrict__ partials,
    int n_rows)
{
    const int tid  = threadIdx.x;
    const int lane = tid & 63;
    const int wave = tid >> 6;
    const int wave_id = (blockIdx.x * blockDim.x + tid) >> 6;
    const int n_waves = (gridDim.x * blockDim.x) >> 6;

    // Per-lane one-hot weights: class index + 1 (bias so class 0 is nonzero).
    const float wb = (float)(4 * lane + 1);
    const floatx4 w0 = {wb,          wb + 1.f,        wb + 2.f,        wb + 3.f};
    const floatx4 w1 = {wb + 256.f,  wb + 257.f,      wb + 258.f,      wb + 259.f};
    const floatx4 w2 = {wb + 512.f,  wb + 513.f,      wb + 514.f,      wb + 515.f};
    const floatx4 w3 = {wb + 768.f,  wb + 769.f,      wb + 770.f,      wb + 771.f};

    float acc = 0.0f;

    floatx4 af0, af1, af2, af3, al0, al1, al2, al3;   // set A
    floatx4 bf0, bf1, bf2, bf3, bl0, bl1, bl2, bl3;   // set B

    #define LOAD_ROW(F0, F1, F2, F3, L0, L1, L2, L3, ROW) do {                     \
        const floatx4* frow_ = (const floatx4*)(features + (size_t)(ROW) * EMBED); \
        F0 = frow_[lane];        F1 = frow_[lane + 64];                            \
        F2 = frow_[lane + 128];  F3 = frow_[lane + 192];                           \
        const floatx4* lrow_ = (const floatx4*)(labels + (size_t)(ROW) * N_CLASSES); \
        L0 = lrow_[lane];        L1 = lrow_[lane + 64];                            \
        L2 = lrow_[lane + 128];                                                    \
        L3 = (lane < N_CLASSES / 4 - 192) ? lrow_[lane + 192]                      \
                                          : (floatx4){0.f, 0.f, 0.f, 0.f};         \
    } while (0)

    // Consume row in (F*,L*); prefetch row RN into (NF*,NL*).
    // Issue order inside: proto loads (4) -> sched_barrier -> prefetch (8).
    #define CONSUME_PREFETCH(F0, F1, F2, F3, L0, L1, L2, L3,                       \
                             NF0, NF1, NF2, NF3, NL0, NL1, NL2, NL3, RN) do {      \
        /* weighted one-hot dot: exact integer (class+1) in fp32 */                \
        float candf = L0.x*w0.x + L0.y*w0.y + L0.z*w0.z + L0.w*w0.w;               \
        candf += L1.x*w1.x + L1.y*w1.y + L1.z*w1.z + L1.w*w1.w;                    \
        candf += L2.x*w2.x + L2.y*w2.y + L2.z*w2.z + L2.w*w2.w;                    \
        candf += L3.x*w3.x + L3.y*w3.y + L3.z*w3.z + L3.w*w3.w;                    \
        unsigned long long m_ = __ballot(candf != 0.0f);                           \
        float clsf = __shfl(candf, __ffsll(m_) - 1, 64);                           \
        int cls = __builtin_amdgcn_readfirstlane((int)clsf - 1);                   \
        const floatx4* prow_ = (const floatx4*)(mean_class + (size_t)cls * EMBED); \
        floatx4 p0 = prow_[lane];                                                  \
        floatx4 p1 = prow_[lane + 64];                                             \
        floatx4 p2 = prow_[lane + 128];                                            \
        floatx4 p3 = prow_[lane + 192];                                            \
        __builtin_amdgcn_sched_barrier(0);  /* pin: proto loads issue first */     \
        if ((RN) < n_rows)                                                         \
            LOAD_ROW(NF0, NF1, NF2, NF3, NL0, NL1, NL2, NL3, RN);                  \
        float ff = 0.f, pp = 0.f, fp = 0.f;                                        \
        ff += F0.x*F0.x + F0.y*F0.y + F0.z*F0.z + F0.w*F0.w;                       \
        pp += p0.x*p0.x + p0.y*p0.y + p0.z*p0.z + p0.w*p0.w;                       \
        fp += F0.x*p0.x + F0.y*p0.y + F0.z*p0.z + F0.w*p0.w;                       \
        ff += F1.x*F1.x + F1.y*F1.y + F1.z*F1.z + F1.w*F1.w;                       \
        pp += p1.x*p1.x + p1.y*p1.y + p1.z*p1.z + p1.w*p1.w;                       \
        fp += F1.x*p1.x + F1.y*p1.y + F1.z*p1.z + F1.w*p1.w;                       \
        ff += F2.x*F2.x + F2.y*F2.y + F2.z*F2.z + F2.w*F2.w;                       \
        pp += p2.x*p2.x + p2.y*p2.y + p2.z*p2.z + p2.w*p2.w;                       \
        fp += F2.x*p2.x + F2.y*p2.y + F2.z*p2.z + F2.w*p2.w;                       \
        ff += F3.x*F3.x + F3.y*F3.y + F3.z*F3.z + F3.w*F3.w;                       \
        pp += p3.x*p3.x + p3.y*p3.y + p3.z*p3.z + p3.w*p3.w;                       \
        fp += F3.x*p3.x + F3.y*p3.y + F3.z*p3.z + F3.w*p3.w;                       \
        _Pragma("unroll")                                                          \
        for (int msk_ = 1; msk_ < 64; msk_ <<= 1) {                                \
            ff += __shfl_xor(ff, msk_, 64);                                        \
            pp += __shfl_xor(pp, msk_, 64);                                        \
            fp += __shfl_xor(fp, msk_, 64);                                        \
        }                                                                          \
        acc += 1.0f - fp * __builtin_amdgcn_rsqf(fmaxf(ff * pp, 1e-24f));          \
    } while (0)

    int r = wave_id;
    if (r < n_rows) LOAD_ROW(af0, af1, af2, af3, al0, al1, al2, al3, r);

    while (r < n_rows) {
        int rn = r + n_waves;
        CONSUME_PREFETCH(af0, af1, af2, af3, al0, al1, al2, al3,
                         bf0, bf1, bf2, bf3, bl0, bl1, bl2, bl3, rn);
        r = rn;
        if (r >= n_rows) break;

        rn = r + n_waves;
        CONSUME_PREFETCH(bf0, bf1, bf2, bf3, bl0, bl1, bl2, bl3,
                         af0, af1, af2, af3, al0, al1, al2, al3, rn);
        r = rn;
    }

    #undef LOAD_ROW
    #undef CONSUME_PREFETCH

    __shared__ float s_red[4];
    if (lane == 0) s_red[wave] = acc;
    __syncthreads();
    if (tid == 0)
        partials[blockIdx.x] = s_red[0] + s_red[1] + s_red[2] + s_red[3];
}

__global__ __launch_bounds__(256) void reduce_partials_kernel(
    const float* __restrict__ partials, int num_partials,
    float* __restrict__ out, float inv_n)
{
    const int tid  = threadIdx.x;
    const int lane = tid & 63;
    const int wave = tid >> 6;
    __shared__ float s_red[4];

    float acc = 0.0f;
    for (int i = tid; i < num_partials; i += 256)
        acc += partials[i];
    #pragma unroll
    for (int msk = 1; msk < 64; msk <<= 1)
        acc += __shfl_xor(acc, msk, 64);
    if (lane == 0) s_red[wave] = acc;
    __syncthreads();
    if (tid == 0)
        out[0] = (s_red[0] + s_red[1] + s_red[2] + s_red[3]) * inv_n;
}

extern "C" void kernel_launch(void* const* d_in, const int* in_sizes, int n_in,
                              void* d_out, int out_size, void* d_ws, size_t ws_size,
                              hipStream_t stream) {
    const float* features   = (const float*)d_in[0];
    const float* labels     = (const float*)d_in[1];
    const float* mean_class = (const float*)d_in[2];
    float* out = (float*)d_out;
    float* partials = (float*)d_ws;

    const int n_rows = in_sizes[0] / EMBED;   // 32768
    const int num_blocks = 1024;              // 4096 persistent waves, 8 rows each

    angular_pipelined_kernel<<<num_blocks, 256, 0, stream>>>(
        features, labels, mean_class, partials, n_rows);
    reduce_partials_kernel<<<1, 256, 0, stream>>>(
        partials, num_blocks, out, 1.0f / (float)n_rows);
}

// Round 4
// 262.147 us; speedup vs baseline: 1.0748x; 1.0748x over previous
//
#include <hip/hip_runtime.h>

constexpr int N_CLASSES = 1000;   // 250 float4 per label row
constexpr int EMBED     = 1024;   // 256 float4 per row; 4 float4 per lane

typedef float floatx4 __attribute__((ext_vector_type(4)));

struct RowRec { int cls; float pp; };   // per-row class + prototype squared norm

__device__ __forceinline__ floatx4 ntload(const floatx4* p) {
    return __builtin_nontemporal_load(p);
}

// ---------- Kernel 1: per-class squared norms (1000 waves, one class each).
// Same accumulation + butterfly order as the previously-passing fused kernel.
__global__ __launch_bounds__(256) void class_norm_kernel(
    const float* __restrict__ mean_class, float* __restrict__ pp_out)
{
    const int tid  = threadIdx.x;
    const int lane = tid & 63;
    const int wid  = (blockIdx.x * blockDim.x + tid) >> 6;
    if (wid >= N_CLASSES) return;
    const floatx4* prow = (const floatx4*)(mean_class + (size_t)wid * EMBED);
    floatx4 p0 = prow[lane];
    floatx4 p1 = prow[lane + 64];
    floatx4 p2 = prow[lane + 128];
    floatx4 p3 = prow[lane + 192];
    float pp = 0.f;
    pp += p0.x*p0.x + p0.y*p0.y + p0.z*p0.z + p0.w*p0.w;
    pp += p1.x*p1.x + p1.y*p1.y + p1.z*p1.z + p1.w*p1.w;
    pp += p2.x*p2.x + p2.y*p2.y + p2.z*p2.z + p2.w*p2.w;
    pp += p3.x*p3.x + p3.y*p3.y + p3.z*p3.z + p3.w*p3.w;
    #pragma unroll
    for (int m = 1; m < 64; m <<= 1) pp += __shfl_xor(pp, m, 64);
    if (lane == 0) pp_out[wid] = pp;
}

// ---------- Kernel 2: label scan (pure 131 MB nt stream -> {cls,pp} per row)
__global__ __launch_bounds__(256, 4) void label_scan_kernel(
    const float* __restrict__ labels,
    const float* __restrict__ pp_arr,
    RowRec* __restrict__ rec, int n_rows)
{
    const int tid  = threadIdx.x;
    const int lane = tid & 63;
    const int wave_id = (blockIdx.x * blockDim.x + tid) >> 6;
    const int n_waves = (gridDim.x * blockDim.x) >> 6;

    // Per-lane one-hot weights: class index + 1 (bias so class 0 is nonzero).
    const float wb = (float)(4 * lane + 1);
    const floatx4 w0 = {wb,          wb + 1.f,   wb + 2.f,   wb + 3.f};
    const floatx4 w1 = {wb + 256.f,  wb + 257.f, wb + 258.f, wb + 259.f};
    const floatx4 w2 = {wb + 512.f,  wb + 513.f, wb + 514.f, wb + 515.f};
    const floatx4 w3 = {wb + 768.f,  wb + 769.f, wb + 770.f, wb + 771.f};

    floatx4 a0, a1, a2, a3, b0, b1, b2, b3;

    #define LOADL(L0, L1, L2, L3, ROW) do {                                        \
        const floatx4* lr_ = (const floatx4*)(labels + (size_t)(ROW) * N_CLASSES); \
        L0 = ntload(lr_ + lane);       L1 = ntload(lr_ + lane + 64);               \
        L2 = ntload(lr_ + lane + 128);                                             \
        L3 = (lane < N_CLASSES / 4 - 192) ? ntload(lr_ + lane + 192)               \
                                          : (floatx4){0.f, 0.f, 0.f, 0.f};         \
    } while (0)

    #define SCANROW(L0, L1, L2, L3, ROW) do {                                      \
        float c_ = L0.x*w0.x + L0.y*w0.y + L0.z*w0.z + L0.w*w0.w;                  \
        c_ += L1.x*w1.x + L1.y*w1.y + L1.z*w1.z + L1.w*w1.w;                       \
        c_ += L2.x*w2.x + L2.y*w2.y + L2.z*w2.z + L2.w*w2.w;                       \
        c_ += L3.x*w3.x + L3.y*w3.y + L3.z*w3.z + L3.w*w3.w;                       \
        unsigned long long m_ = __ballot(c_ != 0.0f);                              \
        float cf_ = __shfl(c_, __ffsll(m_) - 1, 64);                               \
        int cls_ = (int)cf_ - 1;                                                   \
        if (lane == 0) {                                                           \
            RowRec rr_; rr_.cls = cls_; rr_.pp = pp_arr[cls_];                     \
            rec[ROW] = rr_;                                                        \
        }                                                                          \
    } while (0)

    int r = wave_id;
    if (r < n_rows) LOADL(a0, a1, a2, a3, r);
    while (r < n_rows) {
        int rn = r + n_waves;
        if (rn < n_rows) LOADL(b0, b1, b2, b3, rn);
        SCANROW(a0, a1, a2, a3, r);
        r = rn;
        if (r >= n_rows) break;
        rn = r + n_waves;
        if (rn < n_rows) LOADL(a0, a1, a2, a3, rn);
        SCANROW(b0, b1, b2, b3, r);
        r = rn;
    }
    #undef LOADL
    #undef SCANROW
}

// ---------- Kernel 3: feature stream + proto gather (addresses known 2 ahead)
__global__ __launch_bounds__(256, 4) void feature_dot_kernel(
    const float* __restrict__ features,
    const float* __restrict__ mean_class,
    const RowRec* __restrict__ rec,
    float* __restrict__ partials, int n_rows)
{
    const int tid  = threadIdx.x;
    const int lane = tid & 63;
    const int wave = tid >> 6;
    const int wave_id = (blockIdx.x * blockDim.x + tid) >> 6;
    const int n_waves = (gridDim.x * blockDim.x) >> 6;

    float acc = 0.0f;

    floatx4 fa0, fa1, fa2, fa3, pa0, pa1, pa2, pa3;   // stage A
    floatx4 fb0, fb1, fb2, fb3, pb0, pb1, pb2, pb3;   // stage B

    #define LOADF(F0, F1, F2, F3, ROW) do {                                        \
        const floatx4* fr_ = (const floatx4*)(features + (size_t)(ROW) * EMBED);   \
        F0 = ntload(fr_ + lane);       F1 = ntload(fr_ + lane + 64);               \
        F2 = ntload(fr_ + lane + 128); F3 = ntload(fr_ + lane + 192);              \
    } while (0)

    #define LOADP(P0, P1, P2, P3, CLS) do {                                        \
        int c_ = __builtin_amdgcn_readfirstlane(CLS);                              \
        const floatx4* pr_ = (const floatx4*)(mean_class + (size_t)c_ * EMBED);    \
        P0 = pr_[lane];       P1 = pr_[lane + 64];                                 \
        P2 = pr_[lane + 128]; P3 = pr_[lane + 192];                                \
    } while (0)

    #define CONSUME(F0, F1, F2, F3, P0, P1, P2, P3, PP) do {                       \
        float ff = 0.f, fp = 0.f;                                                  \
        ff += F0.x*F0.x + F0.y*F0.y + F0.z*F0.z + F0.w*F0.w;                       \
        fp += F0.x*P0.x + F0.y*P0.y + F0.z*P0.z + F0.w*P0.w;                       \
        ff += F1.x*F1.x + F1.y*F1.y + F1.z*F1.z + F1.w*F1.w;                       \
        fp += F1.x*P1.x + F1.y*P1.y + F1.z*P1.z + F1.w*P1.w;                       \
        ff += F2.x*F2.x + F2.y*F2.y + F2.z*F2.z + F2.w*F2.w;                       \
        fp += F2.x*P2.x + F2.y*P2.y + F2.z*P2.z + F2.w*P2.w;                       \
        ff += F3.x*F3.x + F3.y*F3.y + F3.z*F3.z + F3.w*F3.w;                       \
        fp += F3.x*P3.x + F3.y*P3.y + F3.z*P3.z + F3.w*P3.w;                       \
        _Pragma("unroll")                                                          \
        for (int m_ = 1; m_ < 64; m_ <<= 1) {                                      \
            ff += __shfl_xor(ff, m_, 64);                                          \
            fp += __shfl_xor(fp, m_, 64);                                          \
        }                                                                          \
        acc += 1.0f - fp * __builtin_amdgcn_rsqf(fmaxf(ff * (PP), 1e-24f));        \
    } while (0)

    int r = wave_id;
    RowRec recA, recB, recC;
    if (r < n_rows) {
        recA = rec[r];                                // row r
        int r1 = r + n_waves;
        if (r1 < n_rows) recB = rec[r1];              // row r+nw
        LOADF(fa0, fa1, fa2, fa3, r);
        LOADP(pa0, pa1, pa2, pa3, recA.cls);
    }

    // invariant each iteration: consume stage X = row r (rec in recA);
    // prefetch other stage = row r+nw (rec in recB); load recC = rec[r+2nw].
    while (r < n_rows) {
        int rn = r + n_waves;
        if (rn < n_rows) {
            LOADF(fb0, fb1, fb2, fb3, rn);
            LOADP(pb0, pb1, pb2, pb3, recB.cls);
            int rnn = rn + n_waves;
            if (rnn < n_rows) recC = rec[rnn];
        }
        CONSUME(fa0, fa1, fa2, fa3, pa0, pa1, pa2, pa3, recA.pp);
        recA = recB; recB = recC;
        r = rn;
        if (r >= n_rows) break;

        rn = r + n_waves;
        if (rn < n_rows) {
            LOADF(fa0, fa1, fa2, fa3, rn);
            LOADP(pa0, pa1, pa2, pa3, recB.cls);
            int rnn = rn + n_waves;
            if (rnn < n_rows) recC = rec[rnn];
        }
        CONSUME(fb0, fb1, fb2, fb3, pb0, pb1, pb2, pb3, recA.pp);
        recA = recB; recB = recC;
        r = rn;
    }
    #undef LOADF
    #undef LOADP
    #undef CONSUME

    __shared__ float s_red[4];
    if (lane == 0) s_red[wave] = acc;
    __syncthreads();
    if (tid == 0)
        partials[blockIdx.x] = s_red[0] + s_red[1] + s_red[2] + s_red[3];
}

__global__ __launch_bounds__(256) void reduce_partials_kernel(
    const float* __restrict__ partials, int num_partials,
    float* __restrict__ out, float inv_n)
{
    const int tid  = threadIdx.x;
    const int lane = tid & 63;
    const int wave = tid >> 6;
    __shared__ float s_red[4];

    float acc = 0.0f;
    for (int i = tid; i < num_partials; i += 256)
        acc += partials[i];
    #pragma unroll
    for (int msk = 1; msk < 64; msk <<= 1)
        acc += __shfl_xor(acc, msk, 64);
    if (lane == 0) s_red[wave] = acc;
    __syncthreads();
    if (tid == 0)
        out[0] = (s_red[0] + s_red[1] + s_red[2] + s_red[3]) * inv_n;
}

extern "C" void kernel_launch(void* const* d_in, const int* in_sizes, int n_in,
                              void* d_out, int out_size, void* d_ws, size_t ws_size,
                              hipStream_t stream) {
    const float* features   = (const float*)d_in[0];
    const float* labels     = (const float*)d_in[1];
    const float* mean_class = (const float*)d_in[2];
    float* out = (float*)d_out;

    float*  partials = (float*)d_ws;                          // 4 KB
    float*  pp_arr   = (float*)((char*)d_ws + 4096);          // 4 KB
    RowRec* rec      = (RowRec*)((char*)d_ws + 8192);         // 256 KB

    const int n_rows = in_sizes[0] / EMBED;   // 32768
    const int num_blocks = 1024;              // 4096 waves, 8 rows each

    class_norm_kernel<<<(N_CLASSES * 64 + 255) / 256, 256, 0, stream>>>(
        mean_class, pp_arr);
    label_scan_kernel<<<num_blocks, 256, 0, stream>>>(
        labels, pp_arr, rec, n_rows);
    feature_dot_kernel<<<num_blocks, 256, 0, stream>>>(
        features, mean_class, rec, partials, n_rows);
    reduce_partials_kernel<<<1, 256, 0, stream>>>(
        partials, num_blocks, out, 1.0f / (float)n_rows);
}

// Round 5
// 258.903 us; speedup vs baseline: 1.0883x; 1.0125x over previous
//
#include <hip/hip_runtime.h>

constexpr int N_CLASSES = 1000;   // 250 float4 per label row
constexpr int EMBED     = 1024;   // 256 float4 per row; 4 float4 per lane

typedef float floatx4 __attribute__((ext_vector_type(4)));

__device__ __forceinline__ floatx4 ntload(const floatx4* p) {
    return __builtin_nontemporal_load(p);
}

// ---------- Kernel 1: label scan — pure 131 MB nt stream -> cls per row.
// Single-buffered, <=64 VGPR, 8 waves/SIMD, 2048 blocks = 32 waves/CU.
// Latency hiding comes from TLP (occupancy), not per-wave pipelining.
__global__ __launch_bounds__(256, 8) void label_scan_kernel(
    const float* __restrict__ labels,
    int* __restrict__ cls_arr, int n_rows)
{
    const int tid  = threadIdx.x;
    const int lane = tid & 63;
    const int wave_id = (blockIdx.x * blockDim.x + tid) >> 6;
    const int n_waves = (gridDim.x * blockDim.x) >> 6;

    // Per-lane one-hot weights: class index + 1 (bias so class 0 is nonzero).
    const float wb = (float)(4 * lane + 1);
    const floatx4 w0 = {wb,          wb + 1.f,   wb + 2.f,   wb + 3.f};
    const floatx4 w1 = {wb + 256.f,  wb + 257.f, wb + 258.f, wb + 259.f};
    const floatx4 w2 = {wb + 512.f,  wb + 513.f, wb + 514.f, wb + 515.f};
    const floatx4 w3 = {wb + 768.f,  wb + 769.f, wb + 770.f, wb + 771.f};

    for (int r = wave_id; r < n_rows; r += n_waves) {
        const floatx4* lr = (const floatx4*)(labels + (size_t)r * N_CLASSES);
        floatx4 l0 = ntload(lr + lane);
        floatx4 l1 = ntload(lr + lane + 64);
        floatx4 l2 = ntload(lr + lane + 128);
        floatx4 l3 = (lane < N_CLASSES / 4 - 192) ? ntload(lr + lane + 192)
                                                  : (floatx4){0.f, 0.f, 0.f, 0.f};
        // weighted one-hot dot: exact integer (class+1) in fp32
        float c = l0.x*w0.x + l0.y*w0.y + l0.z*w0.z + l0.w*w0.w;
        c += l1.x*w1.x + l1.y*w1.y + l1.z*w1.z + l1.w*w1.w;
        c += l2.x*w2.x + l2.y*w2.y + l2.z*w2.z + l2.w*w2.w;
        c += l3.x*w3.x + l3.y*w3.y + l3.z*w3.z + l3.w*w3.w;
        unsigned long long m = __ballot(c != 0.0f);
        float cf = __shfl(c, __ffsll(m) - 1, 64);
        if (lane == 0) cls_arr[r] = (int)cf - 1;
    }
}

// ---------- Kernel 2: feature stream + proto gather (cls known 1 row ahead).
// Single-buffered data, <=64 VGPR, 32 waves/CU. pp computed inline from the
// proto regs (same accumulation + butterfly order as the R0-passing kernel).
__global__ __launch_bounds__(256, 8) void feature_dot_kernel(
    const float* __restrict__ features,
    const float* __restrict__ mean_class,
    const int* __restrict__ cls_arr,
    float* __restrict__ partials, int n_rows)
{
    const int tid  = threadIdx.x;
    const int lane = tid & 63;
    const int wave = tid >> 6;
    const int wave_id = (blockIdx.x * blockDim.x + tid) >> 6;
    const int n_waves = (gridDim.x * blockDim.x) >> 6;

    float acc = 0.0f;

    int r = wave_id;
    int cls_cur = (r < n_rows) ? cls_arr[r] : 0;   // uniform broadcast load

    for (; r < n_rows; r += n_waves) {
        const int rn = r + n_waves;

        // issue all bulk loads for this row up front
        const floatx4* fr = (const floatx4*)(features + (size_t)r * EMBED);
        floatx4 f0 = ntload(fr + lane);
        floatx4 f1 = ntload(fr + lane + 64);
        floatx4 f2 = ntload(fr + lane + 128);
        floatx4 f3 = ntload(fr + lane + 192);

        const int c = __builtin_amdgcn_readfirstlane(cls_cur);
        const floatx4* pr = (const floatx4*)(mean_class + (size_t)c * EMBED);
        floatx4 p0 = pr[lane];
        floatx4 p1 = pr[lane + 64];
        floatx4 p2 = pr[lane + 128];
        floatx4 p3 = pr[lane + 192];

        // prefetch next row's class while loads are in flight
        int cls_nxt = (rn < n_rows) ? cls_arr[rn] : 0;

        float ff = 0.f, pp = 0.f, fp = 0.f;
        ff += f0.x*f0.x + f0.y*f0.y + f0.z*f0.z + f0.w*f0.w;
        pp += p0.x*p0.x + p0.y*p0.y + p0.z*p0.z + p0.w*p0.w;
        fp += f0.x*p0.x + f0.y*p0.y + f0.z*p0.z + f0.w*p0.w;
        ff += f1.x*f1.x + f1.y*f1.y + f1.z*f1.z + f1.w*f1.w;
        pp += p1.x*p1.x + p1.y*p1.y + p1.z*p1.z + p1.w*p1.w;
        fp += f1.x*p1.x + f1.y*p1.y + f1.z*p1.z + f1.w*p1.w;
        ff += f2.x*f2.x + f2.y*f2.y + f2.z*f2.z + f2.w*f2.w;
        pp += p2.x*p2.x + p2.y*p2.y + p2.z*p2.z + p2.w*p2.w;
        fp += f2.x*p2.x + f2.y*p2.y + f2.z*p2.z + f2.w*p2.w;
        ff += f3.x*f3.x + f3.y*f3.y + f3.z*f3.z + f3.w*f3.w;
        pp += p3.x*p3.x + p3.y*p3.y + p3.z*p3.z + p3.w*p3.w;
        fp += f3.x*p3.x + f3.y*p3.y + f3.z*p3.z + f3.w*p3.w;
        #pragma unroll
        for (int msk = 1; msk < 64; msk <<= 1) {
            ff += __shfl_xor(ff, msk, 64);
            pp += __shfl_xor(pp, msk, 64);
            fp += __shfl_xor(fp, msk, 64);
        }
        acc += 1.0f - fp * __builtin_amdgcn_rsqf(fmaxf(ff * pp, 1e-24f));

        cls_cur = cls_nxt;
    }

    __shared__ float s_red[4];
    if (lane == 0) s_red[wave] = acc;
    __syncthreads();
    if (tid == 0)
        partials[blockIdx.x] = s_red[0] + s_red[1] + s_red[2] + s_red[3];
}

__global__ __launch_bounds__(256) void reduce_partials_kernel(
    const float* __restrict__ partials, int num_partials,
    float* __restrict__ out, float inv_n)
{
    const int tid  = threadIdx.x;
    const int lane = tid & 63;
    const int wave = tid >> 6;
    __shared__ float s_red[4];

    float acc = 0.0f;
    for (int i = tid; i < num_partials; i += 256)
        acc += partials[i];
    #pragma unroll
    for (int msk = 1; msk < 64; msk <<= 1)
        acc += __shfl_xor(acc, msk, 64);
    if (lane == 0) s_red[wave] = acc;
    __syncthreads();
    if (tid == 0)
        out[0] = (s_red[0] + s_red[1] + s_red[2] + s_red[3]) * inv_n;
}

extern "C" void kernel_launch(void* const* d_in, const int* in_sizes, int n_in,
                              void* d_out, int out_size, void* d_ws, size_t ws_size,
                              hipStream_t stream) {
    const float* features   = (const float*)d_in[0];
    const float* labels     = (const float*)d_in[1];
    const float* mean_class = (const float*)d_in[2];
    float* out = (float*)d_out;

    float* partials = (float*)d_ws;                     // 8 KB (2048 blocks)
    int*   cls_arr  = (int*)((char*)d_ws + 16384);      // 128 KB

    const int n_rows = in_sizes[0] / EMBED;   // 32768
    const int num_blocks = 2048;              // 8 blocks/CU -> 32 waves/CU

    label_scan_kernel<<<num_blocks, 256, 0, stream>>>(labels, cls_arr, n_rows);
    feature_dot_kernel<<<num_blocks, 256, 0, stream>>>(
        features, mean_class, cls_arr, partials, n_rows);
    reduce_partials_kernel<<<1, 256, 0, stream>>>(
        partials, num_blocks, out, 1.0f / (float)n_rows);
}

// Round 6
// 249.840 us; speedup vs baseline: 1.1278x; 1.0363x over previous
//
#include <hip/hip_runtime.h>

constexpr int N_CLASSES = 1000;   // 250 float4 per label row
constexpr int EMBED     = 1024;   // 256 float4 per row; 4 float4 per lane

typedef float floatx4 __attribute__((ext_vector_type(4)));

__device__ __forceinline__ floatx4 ntload(const floatx4* p) {
    return __builtin_nontemporal_load(p);
}

// Fused single-pass kernel with EARLY-EXIT label scan.
// Labels are one-hot: exactly one nonzero float per 4000 B row. The wave
// scans the row in 1 KB chunks (256 classes each) and stops at the first
// chunk containing the hot element (ballot -> uniform break). Expected
// label bytes drop from 4 KB to ~2.46 KB per row (uniform classes):
// 131 MB -> ~81 MB of HBM reads. Feature loads are issued BEFORE the scan
// so they overlap the serial chunk round-trips. Read rate was shown
// (R0-R5) to be invariant to occupancy/pipelining at ~3.5 TB/s, so bytes
// are the only remaining lever.
__global__ __launch_bounds__(256, 4) void angular_fused_kernel(
    const float* __restrict__ features,
    const float* __restrict__ labels,
    const float* __restrict__ mean_class,
    float* __restrict__ partials,
    int n_rows)
{
    const int tid  = threadIdx.x;
    const int lane = tid & 63;
    const int wave = tid >> 6;
    const int wave_id = (blockIdx.x * blockDim.x + tid) >> 6;
    const int n_waves = (gridDim.x * blockDim.x) >> 6;

    const float wb0 = (float)(4 * lane + 1);   // weight base: class idx + 1

    float acc = 0.0f;

    for (int r = wave_id; r < n_rows; r += n_waves) {
        // ---- issue feature loads first (overlap label-scan latency) ----
        const floatx4* fr = (const floatx4*)(features + (size_t)r * EMBED);
        floatx4 f0 = ntload(fr + lane);
        floatx4 f1 = ntload(fr + lane + 64);
        floatx4 f2 = ntload(fr + lane + 128);
        floatx4 f3 = ntload(fr + lane + 192);

        // ---- early-exit chunked label scan ----
        const floatx4* lr = (const floatx4*)(labels + (size_t)r * N_CLASSES);
        int cls = 0;
        #pragma unroll
        for (int ch = 0; ch < 4; ++ch) {
            floatx4 l;
            if (ch < 3) {
                l = ntload(lr + lane + 64 * ch);
            } else {
                l = (lane < N_CLASSES / 4 - 192) ? ntload(lr + lane + 192)
                                                 : (floatx4){0.f, 0.f, 0.f, 0.f};
            }
            // weighted one-hot dot within chunk: exact integer (class+1)
            const float base = wb0 + 256.0f * ch;
            float c = l.x * base + l.y * (base + 1.0f)
                    + l.z * (base + 2.0f) + l.w * (base + 3.0f);
            unsigned long long m = __ballot(c != 0.0f);
            if (m) {   // wave-uniform: hot element found in this chunk
                float cf = __shfl(c, __ffsll(m) - 1, 64);
                cls = (int)cf - 1;
                break;
            }
        }
        cls = __builtin_amdgcn_readfirstlane(cls);

        // ---- prototype gather (L2/L3-hot, cached) + dots ----
        const floatx4* pr = (const floatx4*)(mean_class + (size_t)cls * EMBED);
        floatx4 p0 = pr[lane];
        floatx4 p1 = pr[lane + 64];
        floatx4 p2 = pr[lane + 128];
        floatx4 p3 = pr[lane + 192];

        float ff = 0.f, pp = 0.f, fp = 0.f;
        ff += f0.x*f0.x + f0.y*f0.y + f0.z*f0.z + f0.w*f0.w;
        pp += p0.x*p0.x + p0.y*p0.y + p0.z*p0.z + p0.w*p0.w;
        fp += f0.x*p0.x + f0.y*p0.y + f0.z*p0.z + f0.w*p0.w;
        ff += f1.x*f1.x + f1.y*f1.y + f1.z*f1.z + f1.w*f1.w;
        pp += p1.x*p1.x + p1.y*p1.y + p1.z*p1.z + p1.w*p1.w;
        fp += f1.x*p1.x + f1.y*p1.y + f1.z*p1.z + f1.w*p1.w;
        ff += f2.x*f2.x + f2.y*f2.y + f2.z*f2.z + f2.w*f2.w;
        pp += p2.x*p2.x + p2.y*p2.y + p2.z*p2.z + p2.w*p2.w;
        fp += f2.x*p2.x + f2.y*p2.y + f2.z*p2.z + f2.w*p2.w;
        ff += f3.x*f3.x + f3.y*f3.y + f3.z*f3.z + f3.w*f3.w;
        pp += p3.x*p3.x + p3.y*p3.y + p3.z*p3.z + p3.w*p3.w;
        fp += f3.x*p3.x + f3.y*p3.y + f3.z*p3.z + f3.w*p3.w;
        #pragma unroll
        for (int msk = 1; msk < 64; msk <<= 1) {
            ff += __shfl_xor(ff, msk, 64);
            pp += __shfl_xor(pp, msk, 64);
            fp += __shfl_xor(fp, msk, 64);
        }
        acc += 1.0f - fp * __builtin_amdgcn_rsqf(fmaxf(ff * pp, 1e-24f));
    }

    __shared__ float s_red[4];
    if (lane == 0) s_red[wave] = acc;
    __syncthreads();
    if (tid == 0)
        partials[blockIdx.x] = s_red[0] + s_red[1] + s_red[2] + s_red[3];
}

__global__ __launch_bounds__(256) void reduce_partials_kernel(
    const float* __restrict__ partials, int num_partials,
    float* __restrict__ out, float inv_n)
{
    const int tid  = threadIdx.x;
    const int lane = tid & 63;
    const int wave = tid >> 6;
    __shared__ float s_red[4];

    float acc = 0.0f;
    for (int i = tid; i < num_partials; i += 256)
        acc += partials[i];
    #pragma unroll
    for (int msk = 1; msk < 64; msk <<= 1)
        acc += __shfl_xor(acc, msk, 64);
    if (lane == 0) s_red[wave] = acc;
    __syncthreads();
    if (tid == 0)
        out[0] = (s_red[0] + s_red[1] + s_red[2] + s_red[3]) * inv_n;
}

extern "C" void kernel_launch(void* const* d_in, const int* in_sizes, int n_in,
                              void* d_out, int out_size, void* d_ws, size_t ws_size,
                              hipStream_t stream) {
    const float* features   = (const float*)d_in[0];
    const float* labels     = (const float*)d_in[1];
    const float* mean_class = (const float*)d_in[2];
    float* out = (float*)d_out;
    float* partials = (float*)d_ws;

    const int n_rows = in_sizes[0] / EMBED;   // 32768
    const int num_blocks = 1024;              // 4096 persistent waves, 8 rows each

    angular_fused_kernel<<<num_blocks, 256, 0, stream>>>(
        features, labels, mean_class, partials, n_rows);
    reduce_partials_kernel<<<1, 256, 0, stream>>>(
        partials, num_blocks, out, 1.0f / (float)n_rows);
}